// Round 12
// baseline (556.136 us; speedup 1.0000x reference)
//
#include <hip/hip_runtime.h>
#include <stdint.h>

typedef unsigned short u16;
typedef unsigned char u8;
typedef unsigned long long u64;
typedef __attribute__((ext_vector_type(8))) short bf16x8;
typedef __attribute__((ext_vector_type(4))) float f32x4;
typedef __attribute__((ext_vector_type(16))) float f32x16;

#define KLOG2E 0.18033688011112043f   // SCALE(0.125) * log2(e)
#define QSCL 184.66496523378732f      // KLOG2E * 1024
#define SINV 0.0001220703125f         // 2^-13
#define EXP2F(x) __builtin_amdgcn_exp2f(x)
#define WAITV(n) asm volatile("s_waitcnt vmcnt(" #n ")" ::: "memory")

__device__ __forceinline__ u16 f2bf(float f) {
  union { float f; unsigned u; } v; v.f = f;
  unsigned r = v.u + 0x7fffu + ((v.u >> 16) & 1u);
  return (u16)(r >> 16);
}
__device__ __forceinline__ float bf2f(u16 u) {
  union { unsigned u; float f; } v; v.u = ((unsigned)u) << 16;
  return v.f;
}
__device__ __forceinline__ u8 f2fp8(float f) {
  return (u8)(__builtin_amdgcn_cvt_pk_fp8_f32(f, f, 0, false) & 0xFF);
}

__device__ __forceinline__ void gload16(const void* g, void* l) {
  __builtin_amdgcn_global_load_lds(
      (const __attribute__((address_space(1))) unsigned int*)g,
      (__attribute__((address_space(3))) unsigned int*)l, 16, 0, 0);
}
__device__ __forceinline__ void gload4(const void* g, void* l) {
  __builtin_amdgcn_global_load_lds(
      (const __attribute__((address_space(1))) unsigned int*)g,
      (__attribute__((address_space(3))) unsigned int*)l, 4, 0, 0);
}

__global__ void cvt_f32_bf16(const float4* __restrict__ s, uint2* __restrict__ d, int n4) {
  int i = blockIdx.x * blockDim.x + threadIdx.x;
  int stride = gridDim.x * blockDim.x;
  for (; i < n4; i += stride) {
    float4 v = s[i];
    uint2 o;
    o.x = (unsigned)f2bf(v.x) | ((unsigned)f2bf(v.y) << 16);
    o.y = (unsigned)f2bf(v.z) | ((unsigned)f2bf(v.w) << 16);
    d[i] = o;
  }
}

// C = A @ B^T, A [M,768] bf16, B [N,768] bf16, 128x128 tile, 4 waves.
// MODE 0: col<768 -> Qb bf16 [row][768]; col>=768 -> Kf8 fp8 x8, with per-row
//         8B-half swap baked (d ^= ((n>>3)&1)<<3) for conflict-free attn reads.
// MODE 1: vT+cb store; MODE 2: f32 C + bias[col].
template <int MODE>
__global__ __launch_bounds__(256, 2) void gemm_bt(
    const u16* __restrict__ A, const u16* __restrict__ Bm,
    void* __restrict__ Cp, void* __restrict__ Cp2,
    const float* __restrict__ bias, int ldc) {
  __shared__ u16 Ab[128 * 32];
  __shared__ u16 Bb[128 * 32];
  const int tid = threadIdx.x;
  const int l = tid & 63, w = tid >> 6;
  const int g = l >> 4, l15 = l & 15;
  const int wr = w >> 1, wc = w & 1;
  const int rowbase = blockIdx.y * 128, colbase = blockIdx.x * 128;

  f32x4 acc[4][4] = {};
  const char* Abase = (const char*)A + (size_t)rowbase * 1536;
  const char* Bbase = (const char*)Bm + (size_t)colbase * 1536;

  for (int kk = 0; kk < 768; kk += 32) {
    __syncthreads();
#pragma unroll
    for (int p = 0; p < 2; ++p) {
      int o = p * 4096 + w * 1024 + l * 16;
      int row = o >> 6, cb = o & 63;
      gload16(Abase + (size_t)row * 1536 + kk * 2 + cb, &Ab[(p * 4096 + w * 1024) / 2]);
      gload16(Bbase + (size_t)row * 1536 + kk * 2 + cb, &Bb[(p * 4096 + w * 1024) / 2]);
    }
    __syncthreads();
    bf16x8 af[4], bfr[4];
#pragma unroll
    for (int i = 0; i < 4; ++i) {
      af[i] = *(const bf16x8*)&Ab[(wr * 64 + i * 16 + l15) * 32 + g * 8];
      bfr[i] = *(const bf16x8*)&Bb[(wc * 64 + i * 16 + l15) * 32 + g * 8];
    }
#pragma unroll
    for (int mi = 0; mi < 4; ++mi)
#pragma unroll
      for (int ni = 0; ni < 4; ++ni)
        acc[mi][ni] = __builtin_amdgcn_mfma_f32_16x16x32_bf16(af[mi], bfr[ni], acc[mi][ni], 0, 0, 0);
  }

#pragma unroll
  for (int mi = 0; mi < 4; ++mi)
#pragma unroll
    for (int ni = 0; ni < 4; ++ni)
#pragma unroll
      for (int r = 0; r < 4; ++r) {
        int row = rowbase + wr * 64 + mi * 16 + g * 4 + r;
        int col = colbase + wc * 64 + ni * 16 + l15;
        float v = acc[mi][ni][r];
        if (MODE == 0) {
          if (col < 768) {
            ((u16*)Cp)[(size_t)row * 768 + col] = f2bf(v);
          } else {
            int d = col - 768;
            int dp = d ^ ((((row) >> 3) & 1) << 3);
            ((u8*)Cp2)[(size_t)row * 768 + dp] = f2fp8(v * 8.0f);
          }
        } else if (MODE == 2) {
          ((float*)Cp)[(size_t)row * ldc + col] = v + bias[col];
        } else {
          int b = col >> 10, nn = col & 1023;
          if (row < 768) {
            ((u16*)Cp)[(size_t)b * 786432 + (size_t)row * 1024 + nn] = f2bf(v + bias[row]);
          } else if (row < 780) {
            ((float*)Cp2)[(size_t)b * 12288 + (size_t)(row - 768) * 1024 + nn] = v * KLOG2E;
          }
        }
      }
}

// Flash attention v12: fp8 32x32x16 QK^T, k-split waves (4 q-groups x 2
// k-halves, split online softmax merged at epilogue), 3-deep K pipeline with
// counted vmcnt, 512 thr, 48KB LDS -> 3 blocks/CU. grid 768 (XCD swizzle).
__global__ __launch_bounds__(512, 6) void attn12(
    const u16* __restrict__ Qb,   // [B*N][768] bf16 (q_shared)
    const u8* __restrict__ Kf8,   // [B*N][768] fp8 e4m3 x8, half-swapped per row
    const u16* __restrict__ vT,   // [B][768][1024] bf16
    const float* __restrict__ cb, // [B][12][1024], pre-scaled by KLOG2E
    const float* __restrict__ Wmix,
    u16* __restrict__ OH)         // [B*N][768] bf16
{
  __shared__ __align__(16) u8 SM[49152];
  u8* KbB = SM;                       // 3 x 8192: K chunk bufs
  u8* VbB = SM + 24576;               // 2 x 8192: V bufs
  float* cbL = (float*)(SM + 40960);  // 1024 f32
  float* MxL = (float*)(SM + 45056);  // [p][e][lane][2] m/l exchange

  const int gid = blockIdx.x;
  const int b = gid & 7;
  const int within = gid >> 3;                  // 0..95
  const int h = within % 12, qt = within / 12;  // qt 0..7
  const int tid = threadIdx.x;
  const int lane = tid & 63, w = tid >> 6;
  const int c = lane & 31, hi = lane >> 5;
  const int p = w & 3, e = w >> 2;
  const int hsw = (c >> 3) & 1;

  const u8* Ksrc = Kf8 + (size_t)b * 786432;
  const char* Vsrc = (const char*)vT + (size_t)(b * 12 + h) * 131072;
  const float* cbp = cb + (size_t)(b * 12 + h) * 1024;

  auto STK = [&](int kt2, int ch2, int buf) {
    int o = tid * 16;  // 512 thr x 16B = 8192B
    int row = o >> 7, t = (o >> 4) & 7;
    gload16(Ksrc + (size_t)(kt2 * 64 + row) * 768 + ch2 * 128 + ((t ^ (row & 7)) * 16),
            KbB + buf * 8192 + o);
  };
  auto STV = [&](int kt2, int buf) {
    int o = tid * 16;
    int row = o >> 7, t = (o >> 4) & 7;
    gload16(Vsrc + (size_t)row * 2048 + kt2 * 128 + ((t ^ (row & 7)) * 16),
            VbB + buf * 8192 + o);
  };

  // ---- prologue stages (FIFO order: cb, cb, K00, V0, K01)
  gload4(cbp + tid, cbL + ((tid >> 6) << 6));
  gload4(cbp + 512 + tid, cbL + 512 + ((tid >> 6) << 6));
  STK(0, 0, 0);
  STV(0, 0);
  STK(0, 1, 1);

  // ---- Q prologue (v10-verified): lane (c,hi): q-row qt*128+p*32+c,
  // B-frag dims D*16 + hi*8 + [0..8)
  long qreg[48];
  {
    const u16* qrow = Qb + ((size_t)b * 1024 + qt * 128 + p * 32 + c) * 768;
    const float* wmh = Wmix + h * 768;
#pragma unroll
    for (int D = 0; D < 48; ++D) {
      int off = D * 16 + hi * 8;
      bf16x8 qv = *(const bf16x8*)(qrow + off);
      float4 w0 = *(const float4*)(wmh + off);
      float4 w1 = *(const float4*)(wmh + off + 4);
      float q0 = bf2f((u16)qv[0]) * (w0.x * QSCL);
      float q1 = bf2f((u16)qv[1]) * (w0.y * QSCL);
      float q2 = bf2f((u16)qv[2]) * (w0.z * QSCL);
      float q3 = bf2f((u16)qv[3]) * (w0.w * QSCL);
      float q4 = bf2f((u16)qv[4]) * (w1.x * QSCL);
      float q5 = bf2f((u16)qv[5]) * (w1.y * QSCL);
      float q6 = bf2f((u16)qv[6]) * (w1.z * QSCL);
      float q7 = bf2f((u16)qv[7]) * (w1.w * QSCL);
      int a = __builtin_amdgcn_cvt_pk_fp8_f32(q0, q1, 0, false);
      a = __builtin_amdgcn_cvt_pk_fp8_f32(q2, q3, a, true);
      int b2 = __builtin_amdgcn_cvt_pk_fp8_f32(q4, q5, 0, false);
      b2 = __builtin_amdgcn_cvt_pk_fp8_f32(q6, q7, b2, true);
      qreg[D] = (long)(((u64)(unsigned)b2 << 32) | (u64)(unsigned)a);
    }
  }

  WAITV(2);                       // cb,cb,K00 done; [V0,K01] in flight
  __builtin_amdgcn_s_barrier();

  float m_run = -1e30f, lpart = 0.f;
  f32x16 oac0 = {}, oac1 = {};

#pragma unroll 1
  for (int kt = 0; kt < 16; ++kt) {
    f32x16 sa = {};
#pragma unroll
    for (int ch = 0; ch < 6; ++ch) {
      // ---- stage (chunk ch+2 of this kt; ch4/ch5 stage kt+1's ch0/ch1+V)
      if (ch <= 3) {
        STK(kt, ch + 2, (ch + 2) % 3);
      } else if (ch == 4) {
        if (kt < 15) STK(kt + 1, 0, 0);
      } else {
        if (kt < 15) { STK(kt + 1, 1, 1); STV(kt + 1, (kt + 1) & 1); }
      }

      // ---- compute chunk ch: 8 MFMAs on wave's k-half rows e*32+c
      __builtin_amdgcn_s_setprio(1);
      const u8* kb0 = KbB + (ch % 3) * 8192 + e * 4096 + c * 128 + ((hi ^ hsw) * 8);
#pragma unroll
      for (int s = 0; s < 8; ++s) {
        long k0 = *(const long*)(kb0 + ((s ^ (c & 7)) << 4));
        sa = __builtin_amdgcn_mfma_f32_32x32x16_fp8_fp8(k0, qreg[ch * 8 + s], sa, 0, 0, 0);
      }
      __builtin_amdgcn_s_setprio(0);

      // ---- counted wait (FIFO-derived; never drains prefetch chain)
      if (ch == 0) { if (kt == 0) { WAITV(1); } else { WAITV(2); } }
      else if (ch <= 3) { WAITV(1); }
      else if (ch == 4) { if (kt < 15) { WAITV(1); } else { WAITV(0); } }
      else { if (kt < 15) { WAITV(2); } }
      __builtin_amdgcn_s_barrier();
    }

    // ---- split online softmax: lane holds k = e*32 + (u&3)+8*(u>>2)+4*hi, q=c
    float cbq[16];
#pragma unroll
    for (int j = 0; j < 4; ++j) {
      float4 t = *(const float4*)&cbL[kt * 64 + e * 32 + 8 * j + 4 * hi];
      cbq[4 * j] = t.x; cbq[4 * j + 1] = t.y; cbq[4 * j + 2] = t.z; cbq[4 * j + 3] = t.w;
    }
    float pmax = -1e30f;
#pragma unroll
    for (int u = 0; u < 16; ++u) {
      sa[u] = fmaf(sa[u], SINV, cbq[u]);
      pmax = fmaxf(pmax, sa[u]);
    }
    pmax = fmaxf(pmax, __shfl_xor(pmax, 32));
    if (__ballot(pmax > m_run)) {
      float mnew = fmaxf(m_run, pmax);
      float alpha = EXP2F(m_run - mnew);
      lpart *= alpha;
      oac0 *= alpha;
      oac1 *= alpha;
      m_run = mnew;
    }
    float rs = 0.f;
#pragma unroll
    for (int u = 0; u < 16; ++u) {
      sa[u] = EXP2F(sa[u] - m_run);
      rs += sa[u];
    }
    rs += __shfl_xor(rs, 32);
    lpart += rs;

    // ---- P pack in-register (v10-verified) + PV: 2 win x 2 dg MFMAs
    const char* vb = (const char*)VbB + (kt & 1) * 8192;
#pragma unroll
    for (int win = 0; win < 2; ++win) {
      unsigned xw, yw, zw, tw;
      asm("v_cvt_pk_bf16_f32 %0, %1, %2" : "=v"(xw) : "v"(sa[win * 8 + 0]), "v"(sa[win * 8 + 1]));
      asm("v_cvt_pk_bf16_f32 %0, %1, %2" : "=v"(yw) : "v"(sa[win * 8 + 2]), "v"(sa[win * 8 + 3]));
      asm("v_cvt_pk_bf16_f32 %0, %1, %2" : "=v"(zw) : "v"(sa[win * 8 + 4]), "v"(sa[win * 8 + 5]));
      asm("v_cvt_pk_bf16_f32 %0, %1, %2" : "=v"(tw) : "v"(sa[win * 8 + 6]), "v"(sa[win * 8 + 7]));
      asm volatile("v_permlane32_swap_b32 %0, %1" : "+v"(xw), "+v"(zw));
      asm volatile("v_permlane32_swap_b32 %0, %1" : "+v"(yw), "+v"(tw));
      union { unsigned u[4]; bf16x8 v; } bu;
      bu.u[0] = xw; bu.u[1] = yw; bu.u[2] = zw; bu.u[3] = tw;
#pragma unroll
      for (int dg = 0; dg < 2; ++dg) {
        int rd = dg * 32 + c;
        int sv = e * 4 + win * 2 + hi;
        bf16x8 vf = *(const bf16x8*)(vb + rd * 128 + ((sv ^ (rd & 7)) * 16));
        if (dg == 0)
          oac0 = __builtin_amdgcn_mfma_f32_32x32x16_bf16(vf, bu.v, oac0, 0, 0, 0);
        else
          oac1 = __builtin_amdgcn_mfma_f32_32x32x16_bf16(vf, bu.v, oac1, 0, 0, 0);
      }
    }
  }

  // ---- epilogue: merge the two k-halves (m*, l rescale), e=0 stores
  MxL[((p * 2 + e) * 64 + lane) * 2 + 0] = m_run;
  MxL[((p * 2 + e) * 64 + lane) * 2 + 1] = lpart;
  __syncthreads();
  float m_o = MxL[((p * 2 + (e ^ 1)) * 64 + lane) * 2 + 0];
  float l_o = MxL[((p * 2 + (e ^ 1)) * 64 + lane) * 2 + 1];
  float mstar = fmaxf(m_run, m_o);
  float sc = EXP2F(m_run - mstar);
  float lfull = lpart * sc + l_o * EXP2F(m_o - mstar);

  float4* MG = (float4*)SM;  // 32KB merge region (aliases Kb + Vb[0]; safe post-barrier)
  if (e == 1) {
#pragma unroll
    for (int j = 0; j < 4; ++j) {
      float4 t0, t1;
      t0.x = oac0[4 * j] * sc;     t0.y = oac0[4 * j + 1] * sc;
      t0.z = oac0[4 * j + 2] * sc; t0.w = oac0[4 * j + 3] * sc;
      t1.x = oac1[4 * j] * sc;     t1.y = oac1[4 * j + 1] * sc;
      t1.z = oac1[4 * j + 2] * sc; t1.w = oac1[4 * j + 3] * sc;
      MG[j * 256 + p * 64 + lane] = t0;
      MG[(4 + j) * 256 + p * 64 + lane] = t1;
    }
  }
  __syncthreads();
  if (e == 0) {
    float rdiv = 1.f / lfull;
    int n = qt * 128 + p * 32 + c;
    size_t nrow = ((size_t)b * 1024 + n) * 768 + h * 64;
#pragma unroll
    for (int j = 0; j < 4; ++j) {
      float4 r0 = MG[j * 256 + p * 64 + lane];
      float4 r1 = MG[(4 + j) * 256 + p * 64 + lane];
      u64 pk0 = (u64)f2bf((oac0[4 * j + 0] * sc + r0.x) * rdiv) |
                ((u64)f2bf((oac0[4 * j + 1] * sc + r0.y) * rdiv) << 16) |
                ((u64)f2bf((oac0[4 * j + 2] * sc + r0.z) * rdiv) << 32) |
                ((u64)f2bf((oac0[4 * j + 3] * sc + r0.w) * rdiv) << 48);
      u64 pk1 = (u64)f2bf((oac1[4 * j + 0] * sc + r1.x) * rdiv) |
                ((u64)f2bf((oac1[4 * j + 1] * sc + r1.y) * rdiv) << 16) |
                ((u64)f2bf((oac1[4 * j + 2] * sc + r1.z) * rdiv) << 32) |
                ((u64)f2bf((oac1[4 * j + 3] * sc + r1.w) * rdiv) << 48);
      *(u64*)&OH[nrow + 8 * j + 4 * hi] = pk0;
      *(u64*)&OH[nrow + 32 + 8 * j + 4 * hi] = pk1;
    }
  }
}

static inline int cvtblocks(int n4) {
  int nb = (n4 + 255) / 256;
  return nb > 2048 ? 2048 : nb;
}

extern "C" void kernel_launch(void* const* d_in, const int* in_sizes, int n_in,
                              void* d_out, int out_size, void* d_ws, size_t ws_size,
                              hipStream_t stream) {
  (void)in_sizes; (void)n_in; (void)out_size; (void)ws_size;
  const float* x = (const float*)d_in[0];
  const float* Wq = (const float*)d_in[1];
  const float* Wk = (const float*)d_in[2];
  const float* Wv = (const float*)d_in[3];
  const float* bv = (const float*)d_in[4];
  const float* Wmix = (const float*)d_in[5];
  const float* Wcb = (const float*)d_in[6];
  const float* Wproj = (const float*)d_in[7];
  const float* bproj = (const float*)d_in[8];
  float* out = (float*)d_out;

  char* ws = (char*)d_ws;
  u16* xbf = (u16*)(ws);                 // 12582912 B
  u16* Wqk = (u16*)(ws + 12582912);      // 2359296 B
  u16* Wvcb = (u16*)(ws + 14942208);     // 1376256 B
  u16* Wpj = (u16*)(ws + 16318464);      // 1179648 B
  u16* Qb = (u16*)(ws + 17498112);       // 12582912 B
  u8* Kf8 = (u8*)(ws + 30081024);        // 6291456 B
  u16* vT = (u16*)(ws + 36372480);       // 12582912 B
  float* cbb = (float*)(ws + 48955392);  // 393216 B
  u16* OH = (u16*)(ws + 49348608);       // 12582912 B (end 61931520)

  cvt_f32_bf16<<<cvtblocks(1572864), 256, 0, stream>>>((const float4*)x, (uint2*)xbf, 1572864);
  cvt_f32_bf16<<<cvtblocks(147456), 256, 0, stream>>>((const float4*)Wq, (uint2*)Wqk, 147456);
  cvt_f32_bf16<<<cvtblocks(147456), 256, 0, stream>>>((const float4*)Wk, (uint2*)(Wqk + 589824), 147456);
  cvt_f32_bf16<<<cvtblocks(147456), 256, 0, stream>>>((const float4*)Wv, (uint2*)Wvcb, 147456);
  cvt_f32_bf16<<<cvtblocks(2304), 256, 0, stream>>>((const float4*)Wcb, (uint2*)(Wvcb + 589824), 2304);
  cvt_f32_bf16<<<cvtblocks(147456), 256, 0, stream>>>((const float4*)Wproj, (uint2*)Wpj, 147456);

  gemm_bt<0><<<dim3(12, 64), 256, 0, stream>>>(xbf, Wqk, Qb, Kf8, nullptr, 0);
  gemm_bt<1><<<dim3(64, 7), 256, 0, stream>>>(Wvcb, xbf, vT, cbb, bv, 0);
  attn12<<<dim3(768), 512, 0, stream>>>(Qb, Kf8, vT, cbb, Wmix, OH);
  gemm_bt<2><<<dim3(6, 64), 256, 0, stream>>>(OH, Wpj, out, nullptr, bproj, 768);
}

// Round 13
// 303.780 us; speedup vs baseline: 1.8307x; 1.8307x over previous
//
#include <hip/hip_runtime.h>
#include <stdint.h>

typedef unsigned short u16;
typedef unsigned char u8;
typedef unsigned long long u64;
typedef __attribute__((ext_vector_type(8))) short bf16x8;
typedef __attribute__((ext_vector_type(4))) float f32x4;

#define KLOG2E 0.18033688011112043f   // SCALE(0.125) * log2(e)
#define QSCL 184.66496523378732f      // KLOG2E * 1024
#define SINV 0.0001220703125f         // 2^-13
#define EXP2F(x) __builtin_amdgcn_exp2f(x)
#define WAITV(n) asm volatile("s_waitcnt vmcnt(" #n ")" ::: "memory")

__device__ __forceinline__ u16 f2bf(float f) {
  union { float f; unsigned u; } v; v.f = f;
  unsigned r = v.u + 0x7fffu + ((v.u >> 16) & 1u);
  return (u16)(r >> 16);
}
__device__ __forceinline__ float bf2f(u16 u) {
  union { unsigned u; float f; } v; v.u = ((unsigned)u) << 16;
  return v.f;
}
__device__ __forceinline__ u8 f2fp8(float f) {
  return (u8)(__builtin_amdgcn_cvt_pk_fp8_f32(f, f, 0, false) & 0xFF);
}
__device__ __forceinline__ long pk64(uint2 v) {
  return (long)(((u64)v.y << 32) | (u64)v.x);
}

__device__ __forceinline__ void gload16(const void* g, void* l) {
  __builtin_amdgcn_global_load_lds(
      (const __attribute__((address_space(1))) unsigned int*)g,
      (__attribute__((address_space(3))) unsigned int*)l, 16, 0, 0);
}
__device__ __forceinline__ void gload4(const void* g, void* l) {
  __builtin_amdgcn_global_load_lds(
      (const __attribute__((address_space(1))) unsigned int*)g,
      (__attribute__((address_space(3))) unsigned int*)l, 4, 0, 0);
}

__global__ void cvt_f32_bf16(const float4* __restrict__ s, uint2* __restrict__ d, int n4) {
  int i = blockIdx.x * blockDim.x + threadIdx.x;
  int stride = gridDim.x * blockDim.x;
  for (; i < n4; i += stride) {
    float4 v = s[i];
    uint2 o;
    o.x = (unsigned)f2bf(v.x) | ((unsigned)f2bf(v.y) << 16);
    o.y = (unsigned)f2bf(v.z) | ((unsigned)f2bf(v.w) << 16);
    d[i] = o;
  }
}

// C = A @ B^T, A [M,768] bf16, B [N,768] bf16, 128x128 tile, 4 waves.
// MODE 0: col<768 -> Qb bf16 [row][768]; col>=768 -> Kf8 fp8 x8, PERMUTED dim order
// MODE 1: vT+cb store; MODE 2: f32 C + bias[col].
template <int MODE>
__global__ __launch_bounds__(256, 2) void gemm_bt(
    const u16* __restrict__ A, const u16* __restrict__ Bm,
    void* __restrict__ Cp, void* __restrict__ Cp2,
    const float* __restrict__ bias, int ldc) {
  __shared__ u16 Ab[128 * 32];
  __shared__ u16 Bb[128 * 32];
  const int tid = threadIdx.x;
  const int l = tid & 63, w = tid >> 6;
  const int g = l >> 4, l15 = l & 15;
  const int wr = w >> 1, wc = w & 1;
  const int rowbase = blockIdx.y * 128, colbase = blockIdx.x * 128;

  f32x4 acc[4][4] = {};
  const char* Abase = (const char*)A + (size_t)rowbase * 1536;
  const char* Bbase = (const char*)Bm + (size_t)colbase * 1536;

  for (int kk = 0; kk < 768; kk += 32) {
    __syncthreads();
#pragma unroll
    for (int p = 0; p < 2; ++p) {
      int o = p * 4096 + w * 1024 + l * 16;
      int row = o >> 6, cb = o & 63;
      gload16(Abase + (size_t)row * 1536 + kk * 2 + cb, &Ab[(p * 4096 + w * 1024) / 2]);
      gload16(Bbase + (size_t)row * 1536 + kk * 2 + cb, &Bb[(p * 4096 + w * 1024) / 2]);
    }
    __syncthreads();
    bf16x8 af[4], bfr[4];
#pragma unroll
    for (int i = 0; i < 4; ++i) {
      af[i] = *(const bf16x8*)&Ab[(wr * 64 + i * 16 + l15) * 32 + g * 8];
      bfr[i] = *(const bf16x8*)&Bb[(wc * 64 + i * 16 + l15) * 32 + g * 8];
    }
#pragma unroll
    for (int mi = 0; mi < 4; ++mi)
#pragma unroll
      for (int ni = 0; ni < 4; ++ni)
        acc[mi][ni] = __builtin_amdgcn_mfma_f32_16x16x32_bf16(af[mi], bfr[ni], acc[mi][ni], 0, 0, 0);
  }

#pragma unroll
  for (int mi = 0; mi < 4; ++mi)
#pragma unroll
    for (int ni = 0; ni < 4; ++ni)
#pragma unroll
      for (int r = 0; r < 4; ++r) {
        int row = rowbase + wr * 64 + mi * 16 + g * 4 + r;
        int col = colbase + wc * 64 + ni * 16 + l15;
        float v = acc[mi][ni][r];
        if (MODE == 0) {
          if (col < 768) {
            ((u16*)Cp)[(size_t)row * 768 + col] = f2bf(v);
          } else {
            int d = col - 768;
            int chunk = d >> 7, w4 = (d >> 5) & 3, gg = (d >> 3) & 3, rr = d & 7;
            int dp = chunk * 128 + gg * 32 + w4 * 8 + rr;
            ((u8*)Cp2)[(size_t)row * 768 + dp] = f2fp8(v * 8.0f);
          }
        } else if (MODE == 2) {
          ((float*)Cp)[(size_t)row * ldc + col] = v + bias[col];
        } else {
          int b = col >> 10, nn = col & 1023;
          if (row < 768) {
            ((u16*)Cp)[(size_t)b * 786432 + (size_t)row * 1024 + nn] = f2bf(v + bias[row]);
          } else if (row < 780) {
            ((float*)Cp2)[(size_t)b * 12288 + (size_t)(row - 768) * 1024 + nn] = v * KLOG2E;
          }
        }
      }
}

// Flash attention v13 = v8 + {2-deep K (stage-1-ahead), cb in LDS, 52KB LDS ->
// 3 blocks/CU (24 waves)}. fp8 QK^T 16x16x32, 8 waves x 16q, counted vmcnt,
// XCD-bijective swizzle. grid 768 x 512 thr.
__global__ __launch_bounds__(512, 6) void attn13(
    const u16* __restrict__ Qb,   // [B*N][768] bf16 (q_shared)
    const u8* __restrict__ Kf8,   // [B*N][768] fp8 e4m3 x8, permuted dims
    const u16* __restrict__ vT,   // [B][768][1024] bf16
    const float* __restrict__ cb, // [B][12][1024], pre-scaled by KLOG2E
    const float* __restrict__ Wmix,
    u16* __restrict__ OH)         // [B*N][768] bf16
{
  __shared__ u8 Kb[2][8192];    // 2-deep: 64 k-rows x 128B fp8 chunk, 16B-slot swz
  __shared__ u16 Vb[2][4096];   // dbuf: [kwin2][64 d][4 slots x 16B]
  __shared__ u16 Pb[8][1024];   // per-wave P: [16 q][64 k] bf16, swz
  __shared__ float cbL[1024];   // whole (b,h) content-bias row

  // XCD-bijective decode: XCD = gid&7 handles batch b = gid&7 exclusively.
  const int gid = blockIdx.x;
  const int b = gid & 7;
  const int within = gid >> 3;     // 0..95
  const int h = within % 12, qt = within / 12;  // qt 0..7
  const int tid = threadIdx.x;
  const int l = tid & 63, w = tid >> 6;
  const int g = l >> 4, l15 = l & 15;

  const u8* Ksrc = Kf8 + (size_t)b * 786432;
  const char* Vsrc = (const char*)vT + (size_t)(b * 12 + h) * 131072;
  const float* cbp = cb + (size_t)(b * 12 + h) * 1024;

  auto STK = [&](int kt, int ch, int buf) {
    int o = tid * 16;  // 512 thr x 16B = 8192B
    int row = o >> 7, t = (o >> 4) & 7;
    gload16(Ksrc + (size_t)(kt * 64 + row) * 768 + ch * 128 + ((t ^ (row & 7)) * 16),
            (char*)Kb[buf] + o);
  };
  auto STV = [&](int kt, int buf) {
    int o = tid * 16;
    int kwin = o >> 12, o2 = o & 4095, d = o2 >> 6, s = (o2 >> 4) & 3;
    gload16(Vsrc + (size_t)d * 2048 + (kt * 64 + kwin * 32 + ((s ^ (d & 3)) * 8)) * 2,
            (char*)Vb[buf] + o);
  };

  // ---- prologue stages: cb x2, K chunk0 -> buf0, K chunk1 -> buf1, V kt0
  gload4(cbp + tid, (char*)cbL + ((tid >> 6) << 8));
  gload4(cbp + 512 + tid, (char*)(cbL + 512) + ((tid >> 6) << 8));
  STK(0, 0, 0);
  STK(0, 1, 1);
  STV(0, 0);

  // ---- Q prologue (overlaps staging): 16 q-rows x 768 d, quantize fp8
  uint2 qreg[24];
  {
    const u16* qrow = Qb + ((size_t)b * 1024 + qt * 128 + w * 16 + l15) * 768;
    const float* wmh = Wmix + h * 768;
#pragma unroll
    for (int wd = 0; wd < 24; ++wd) {
      bf16x8 qv = *(const bf16x8*)(qrow + wd * 32 + g * 8);
      const float* wm = wmh + wd * 32 + g * 8;
      float4 w0 = *(const float4*)wm;
      float4 w1 = *(const float4*)(wm + 4);
      float q0 = bf2f((u16)qv[0]) * (w0.x * QSCL);
      float q1 = bf2f((u16)qv[1]) * (w0.y * QSCL);
      float q2 = bf2f((u16)qv[2]) * (w0.z * QSCL);
      float q3 = bf2f((u16)qv[3]) * (w0.w * QSCL);
      float q4 = bf2f((u16)qv[4]) * (w1.x * QSCL);
      float q5 = bf2f((u16)qv[5]) * (w1.y * QSCL);
      float q6 = bf2f((u16)qv[6]) * (w1.z * QSCL);
      float q7 = bf2f((u16)qv[7]) * (w1.w * QSCL);
      int a = __builtin_amdgcn_cvt_pk_fp8_f32(q0, q1, 0, false);
      a = __builtin_amdgcn_cvt_pk_fp8_f32(q2, q3, a, true);
      int b2 = __builtin_amdgcn_cvt_pk_fp8_f32(q4, q5, 0, false);
      b2 = __builtin_amdgcn_cvt_pk_fp8_f32(q6, q7, b2, true);
      qreg[wd].x = (unsigned)a;
      qreg[wd].y = (unsigned)b2;
    }
  }

  WAITV(0);
  __builtin_amdgcn_s_barrier();

  float m_run = -1e30f, lpart = 0.f;
  f32x4 oacc[4] = {};

#pragma unroll 1
  for (int kt = 0; kt < 16; ++kt) {
    f32x4 sa[4] = {};
#pragma unroll
    for (int ch = 0; ch < 6; ++ch) {
      // ---- stage 1-ahead: chunk ch+1 -> Kb[(ch+1)&1]; V(kt+1) at ch1
      if (ch == 0) { if (kt > 0) STK(kt, 1, 1); }
      else if (ch < 5) STK(kt, ch + 1, (ch + 1) & 1);
      else if (kt < 15) STK(kt + 1, 0, 0);
      if (ch == 1 && kt < 15) STV(kt + 1, (kt + 1) & 1);

      // ---- compute chunk ch from Kb[ch&1]
      __builtin_amdgcn_s_setprio(1);
#pragma unroll
      for (int j = 0; j < 2; ++j) {
        long qf0 = pk64(qreg[ch * 4 + 2 * j]);
        long qf1 = pk64(qreg[ch * 4 + 2 * j + 1]);
        int slot = (2 * g + j) ^ (l15 & 7);
#pragma unroll
        for (int s = 0; s < 4; ++s) {
          uint4 kk = *(const uint4*)&Kb[ch & 1][(16 * s + l15) * 128 + slot * 16];
          long klo = (long)(((u64)kk.y << 32) | kk.x);
          long khi = (long)(((u64)kk.w << 32) | kk.z);
          sa[s] = __builtin_amdgcn_mfma_f32_16x16x32_fp8_fp8(klo, qf0, sa[s], 0, 0, 0);
          sa[s] = __builtin_amdgcn_mfma_f32_16x16x32_fp8_fp8(khi, qf1, sa[s], 0, 0, 0);
        }
      }
      __builtin_amdgcn_s_setprio(0);

      // ---- counted wait (FIFO-derived, 1-ahead pipeline; no mid-loop drains)
      if (ch == 0) { if (kt == 0) { WAITV(0); } else { WAITV(1); } }
      else if (ch == 1) { if (kt < 15) { WAITV(2); } else { WAITV(1); } }
      else if (ch <= 4) { if (kt < 15) { WAITV(2); } else { WAITV(1); } }
      else { if (kt < 15) { WAITV(2); } else { WAITV(0); } }
      __builtin_amdgcn_s_barrier();
    }

    // ---- softmax: lane holds rows k = 16s+4g+r for column q = l15 (cb from LDS)
    float fv[16];
    float pmax = -1e30f;
#pragma unroll
    for (int s = 0; s < 4; ++s) {
      float4 cbv = *(const float4*)&cbL[kt * 64 + s * 16 + g * 4];
      fv[s * 4 + 0] = fmaf(sa[s][0], SINV, cbv.x);
      fv[s * 4 + 1] = fmaf(sa[s][1], SINV, cbv.y);
      fv[s * 4 + 2] = fmaf(sa[s][2], SINV, cbv.z);
      fv[s * 4 + 3] = fmaf(sa[s][3], SINV, cbv.w);
#pragma unroll
      for (int r = 0; r < 4; ++r) pmax = fmaxf(pmax, fv[s * 4 + r]);
    }
    pmax = fmaxf(pmax, __shfl_xor(pmax, 16));
    pmax = fmaxf(pmax, __shfl_xor(pmax, 32));
    if (__ballot(pmax > m_run)) {
      float mnew = fmaxf(m_run, pmax);
      float alpha = EXP2F(m_run - mnew);
      lpart *= alpha;
#pragma unroll
      for (int vf = 0; vf < 4; ++vf) oacc[vf] *= alpha;
      m_run = mnew;
    }
    float rs = 0.f;
#pragma unroll
    for (int r = 0; r < 16; ++r) {
      fv[r] = EXP2F(fv[r] - m_run);
      rs += fv[r];
    }
    rs += __shfl_xor(rs, 16);
    rs += __shfl_xor(rs, 32);
    lpart += rs;

    // ---- P pack -> per-wave LDS (b64 writes, 16B-slot swz)
#pragma unroll
    for (int s = 0; s < 4; ++s) {
      unsigned w01, w23;
      asm("v_cvt_pk_bf16_f32 %0, %1, %2" : "=v"(w01) : "v"(fv[s * 4]), "v"(fv[s * 4 + 1]));
      asm("v_cvt_pk_bf16_f32 %0, %1, %2" : "=v"(w23) : "v"(fv[s * 4 + 2]), "v"(fv[s * 4 + 3]));
      int ts = (2 * s + (g >> 1)) ^ (l15 & 7);
      uint2 uu; uu.x = w01; uu.y = w23;
      *(uint2*)((char*)Pb[w] + l15 * 128 + ts * 16 + (g & 1) * 8) = uu;
    }

    // ---- PV: A = V (16d x 32k) from LDS, B = P from LDS (V of kt: Vb[kt&1])
#pragma unroll
    for (int kwin = 0; kwin < 2; ++kwin) {
      int tr = (4 * kwin + g) ^ (l15 & 7);
      bf16x8 pf = *(const bf16x8*)((const char*)Pb[w] + l15 * 128 + tr * 16);
#pragma unroll
      for (int vf = 0; vf < 4; ++vf) {
        int d = vf * 16 + l15;
        bf16x8 vfrag = *(const bf16x8*)((const char*)Vb[kt & 1] + kwin * 4096 + d * 64 +
                                        ((g ^ (d & 3)) * 16));
        oacc[vf] = __builtin_amdgcn_mfma_f32_16x16x32_bf16(vfrag, pf, oacc[vf], 0, 0, 0);
      }
    }
  }

  // ---- epilogue: lane (q=l15) holds d = vf*16+4g+r; divide by l, store u64
  float rdiv = 1.f / lpart;
  size_t nrow = ((size_t)b * 1024 + qt * 128 + w * 16 + l15) * 768;
#pragma unroll
  for (int vf = 0; vf < 4; ++vf) {
    u64 pk = (u64)f2bf(oacc[vf][0] * rdiv) |
             ((u64)f2bf(oacc[vf][1] * rdiv) << 16) |
             ((u64)f2bf(oacc[vf][2] * rdiv) << 32) |
             ((u64)f2bf(oacc[vf][3] * rdiv) << 48);
    *(u64*)&OH[nrow + h * 64 + vf * 16 + 4 * g] = pk;
  }
}

static inline int cvtblocks(int n4) {
  int nb = (n4 + 255) / 256;
  return nb > 2048 ? 2048 : nb;
}

extern "C" void kernel_launch(void* const* d_in, const int* in_sizes, int n_in,
                              void* d_out, int out_size, void* d_ws, size_t ws_size,
                              hipStream_t stream) {
  (void)in_sizes; (void)n_in; (void)out_size; (void)ws_size;
  const float* x = (const float*)d_in[0];
  const float* Wq = (const float*)d_in[1];
  const float* Wk = (const float*)d_in[2];
  const float* Wv = (const float*)d_in[3];
  const float* bv = (const float*)d_in[4];
  const float* Wmix = (const float*)d_in[5];
  const float* Wcb = (const float*)d_in[6];
  const float* Wproj = (const float*)d_in[7];
  const float* bproj = (const float*)d_in[8];
  float* out = (float*)d_out;

  char* ws = (char*)d_ws;
  u16* xbf = (u16*)(ws);                 // 12582912 B
  u16* Wqk = (u16*)(ws + 12582912);      // 2359296 B
  u16* Wvcb = (u16*)(ws + 14942208);     // 1376256 B
  u16* Wpj = (u16*)(ws + 16318464);      // 1179648 B
  u16* Qb = (u16*)(ws + 17498112);       // 12582912 B
  u8* Kf8 = (u8*)(ws + 30081024);        // 6291456 B
  u16* vT = (u16*)(ws + 36372480);       // 12582912 B
  float* cbb = (float*)(ws + 48955392);  // 393216 B
  u16* OH = (u16*)(ws + 49348608);       // 12582912 B (end 61931520)

  cvt_f32_bf16<<<cvtblocks(1572864), 256, 0, stream>>>((const float4*)x, (uint2*)xbf, 1572864);
  cvt_f32_bf16<<<cvtblocks(147456), 256, 0, stream>>>((const float4*)Wq, (uint2*)Wqk, 147456);
  cvt_f32_bf16<<<cvtblocks(147456), 256, 0, stream>>>((const float4*)Wk, (uint2*)(Wqk + 589824), 147456);
  cvt_f32_bf16<<<cvtblocks(147456), 256, 0, stream>>>((const float4*)Wv, (uint2*)Wvcb, 147456);
  cvt_f32_bf16<<<cvtblocks(2304), 256, 0, stream>>>((const float4*)Wcb, (uint2*)(Wvcb + 589824), 2304);
  cvt_f32_bf16<<<cvtblocks(147456), 256, 0, stream>>>((const float4*)Wproj, (uint2*)Wpj, 147456);

  gemm_bt<0><<<dim3(12, 64), 256, 0, stream>>>(xbf, Wqk, Qb, Kf8, nullptr, 0);
  gemm_bt<1><<<dim3(64, 7), 256, 0, stream>>>(Wvcb, xbf, vT, cbb, bv, 0);
  attn13<<<dim3(768), 512, 0, stream>>>(Qb, Kf8, vT, cbb, Wmix, OH);
  gemm_bt<2><<<dim3(6, 64), 256, 0, stream>>>(OH, Wpj, out, nullptr, bproj, 768);
}